// Round 5
// baseline (1949.619 us; speedup 1.0000x reference)
//
#include <hip/hip_runtime.h>

typedef unsigned short u16;
typedef short bf16x8 __attribute__((ext_vector_type(8)));
typedef float f32x4 __attribute__((ext_vector_type(4)));

typedef const __attribute__((address_space(1))) void* gaddr_t;
typedef __attribute__((address_space(3))) void* laddr_t;

#define NB_INV 64

__device__ __forceinline__ u16 f2b(float f){
  unsigned u = __float_as_uint(f);
  u = (u + 0x7fffu + ((u >> 16) & 1u)) >> 16;
  return (u16)u;
}
__device__ __forceinline__ float b2f(u16 h){
  return __uint_as_float(((unsigned)h) << 16);
}
__device__ __forceinline__ float2 cmul(float2 a, float2 b){
  return make_float2(a.x*b.x - a.y*b.y, a.x*b.y + a.y*b.x);
}

// ---------------- merged cast + small builds ----------------
// WABb = [WA;WX] (2048x1024), MV4 col-interleaved, h0 row of XROLL
__global__ void cast_all(const float* __restrict__ x, const float* __restrict__ wa,
                         const float* __restrict__ wx, const float* __restrict__ wo,
                         const float* __restrict__ vr, const float* __restrict__ vi,
                         const float* __restrict__ lhr, const float* __restrict__ lhi,
                         u16* __restrict__ Xb, u16* __restrict__ WABb,
                         u16* __restrict__ WOb, u16* __restrict__ Mv,
                         u16* __restrict__ xroll){
  int i = blockIdx.x*blockDim.x + threadIdx.x;
  int st = gridDim.x*blockDim.x;
  for (int idx = i; idx < 4981760; idx += st){
    if (idx < 4849664){
      const float* s; u16* d; int o;
      if (idx < 4194304){ s = x; d = Xb; o = idx; }
      else if (idx < 4456448){ s = wa; d = WABb; o = idx - 4194304; }
      else if (idx < 4718592){ s = wx; d = WABb + 1048576; o = idx - 4456448; }
      else { s = wo; d = WOb; o = idx - 4718592; }
      float4 v = ((const float4*)s)[o];
      ushort4 r; r.x=f2b(v.x); r.y=f2b(v.y); r.z=f2b(v.z); r.w=f2b(v.w);
      ((ushort4*)d)[o] = r;
    } else if (idx < 4980736){
      int o = idx - 4849664;            // MV4: 512 rows x 256 ushort4
      int m = o >> 8, q = o & 255;
      float2 a = ((const float2*)vr)[m*256 + q];
      float2 b = ((const float2*)vi)[m*256 + q];
      ushort4 r; r.x=f2b(a.x); r.y=f2b(-b.x); r.z=f2b(a.y); r.w=f2b(-b.y);
      ((ushort4*)Mv)[o] = r;
    } else {
      int o = idx - 4980736;            // h0: 4 batches x 256 ushort4
      int b = o >> 8, c4 = o & 255;
      float4 v = (c4 < 128) ? ((const float4*)lhr)[c4] : ((const float4*)lhi)[c4-128];
      ushort4 r; r.x=f2b(v.x); r.y=f2b(v.y); r.z=f2b(v.z); r.w=f2b(v.w);
      ((ushort4*)xroll)[b*1048576 + c4] = r;
    }
  }
}

// ---------------- 32x32 complex GJ with partial pivoting (256 thr) ----------------
__device__ __forceinline__ void gj32(float2 (&L)[32][33], float2 (&R)[32][33],
                                     float2* fcol, int tid){
  for (int k = 0; k < 32; ++k){
    if (tid < 64){
      int lane = tid;
      float2 colv = make_float2(0.f, 0.f);
      float mag = -1.f;
      if (lane < 32){
        colv = L[lane][k];
        if (lane >= k) mag = colv.x*colv.x + colv.y*colv.y;
      }
      int best = lane;
      #pragma unroll
      for (int off = 1; off < 32; off <<= 1){
        float om = __shfl_xor(mag, off);
        int ob  = __shfl_xor(best, off);
        if (om > mag || (om == mag && ob < best)){ mag = om; best = ob; }
      }
      int p = __shfl(best, 0);
      float pvx = __shfl(colv.x, p), pvy = __shfl(colv.y, p);
      float dinv = 1.f / (pvx*pvx + pvy*pvy);
      float2 pinv = make_float2(pvx*dinv, -pvy*dinv);
      float2 rk = (lane < 32) ? L[k][lane] : R[k][lane-32];
      float2 rp = (lane < 32) ? L[p][lane] : R[p][lane-32];
      float2 nk = cmul(rp, pinv);
      if (lane < 32) L[k][lane] = nk; else R[k][lane-32] = nk;
      if (p != k){ if (lane < 32) L[p][lane] = rk; else R[p][lane-32] = rk; }
      if (lane < 32){
        float2 f = colv;
        float okx = __shfl(colv.x, k), oky = __shfl(colv.y, k);
        if (lane == p){ f.x = okx; f.y = oky; }
        fcol[lane] = f;
      }
    }
    __syncthreads();
    #pragma unroll
    for (int i = 0; i < 8; ++i){
      int idx = tid + i*256;
      int r = idx >> 6, c = idx & 63;
      if (r != k){
        float2 f = fcol[r];
        float2 nk = (c < 32) ? L[k][c] : R[k][c-32];
        float2 cell = (c < 32) ? L[r][c] : R[r][c-32];
        cell.x -= f.x*nk.x - f.y*nk.y;
        cell.y -= f.x*nk.y + f.y*nk.x;
        if (c < 32) L[r][c] = cell; else R[r][c-32] = cell;
      }
    }
    __syncthreads();
  }
}

// ---------------- persistent blocked Gauss-Jordan inversion ----------------
// 64 blocks co-resident; device-scope atomic phase barrier; 16 steps inside.
__global__ __launch_bounds__(256) void inv_persist(
    const float* __restrict__ vr, const float* __restrict__ vi,
    float2* __restrict__ aug, float2* __restrict__ prA, float2* __restrict__ prB,
    float2* __restrict__ bv0, float2* __restrict__ bv1,
    u16* __restrict__ Mi, int* __restrict__ bar)
{
  __shared__ float2 Bi[32][33];
  __shared__ float2 Pr[32][33];
  __shared__ float2 T1[32][33];
  __shared__ float2 Nd[32][33];
  __shared__ float2 Pc[128][33];
  __shared__ float2 fcol[32];
  const int tid = threadIdx.x, blk = blockIdx.x;
  int nbar = 0;

  auto GBAR = [&](){
    __syncthreads();
    __threadfence();
    if (tid == 0){
      ++nbar;
      __hip_atomic_fetch_add(bar, 1, __ATOMIC_ACQ_REL, __HIP_MEMORY_SCOPE_AGENT);
      while (__hip_atomic_load(bar, __ATOMIC_ACQUIRE, __HIP_MEMORY_SCOPE_AGENT) < nbar*NB_INV)
        __builtin_amdgcn_s_sleep(2);
    }
    __syncthreads();
    __threadfence();
  };

  // ---- init aug = [V | I], prow0 = rows 0..31 ----
  for (int i = blk*256 + tid; i < 512*1024; i += NB_INV*256){
    int r = i >> 10, c = i & 1023;
    float2 v = (c < 512) ? make_float2(vr[r*512+c], vi[r*512+c])
                         : make_float2((c-512)==r ? 1.f : 0.f, 0.f);
    aug[i] = v;
    if (r < 32) prA[(size_t)r*1024 + c] = v;
  }
  GBAR();

  // ---- panel 0 (block 0) ----
  if (blk == 0){
    for (int i = tid; i < 1024; i += 256){
      int r = i>>5, c = i&31;
      Nd[r][c] = aug[(size_t)r*1024 + c];
      Pr[r][c] = make_float2((r==c) ? 1.f : 0.f, 0.f);
    }
    __syncthreads();
    gj32(Nd, Pr, fcol, tid);
    for (int i = tid; i < 1024; i += 256) bv0[i] = Pr[i>>5][i&31];
  }
  GBAR();

  // ---- 16 elimination steps ----
  for (int step = 0; step < 16; ++step){
    const int bs = step*32;
    float2* bin   = (step&1) ? bv1 : bv0;
    float2* bout  = (step&1) ? bv0 : bv1;
    float2* prin  = (step&1) ? prB : prA;
    float2* prout = (step&1) ? prA : prB;
    for (int i = tid; i < 1024; i += 256) Bi[i>>5][i&31] = bin[i];
    const int ncs = (992 - bs) >> 5;
    const int ntask = ncs*4;
    const int prg = (bs + 32) >> 7;
    bool havePanel = false;
    for (int t = blk; t < ntask; t += NB_INV){
      const int strip = t >> 2, rg = t & 3;
      const int c0 = bs + 32 + strip*32;
      const int r0 = rg*128;
      const bool panel = (step < 15) && (strip == 0) && (rg == prg);
      __syncthreads();
      for (int i = tid; i < 1024; i += 256)
        Pr[i>>5][i&31] = prin[(size_t)(i>>5)*1024 + c0 + (i&31)];
      for (int i = tid; i < 4096; i += 256)
        Pc[i>>5][i&31] = aug[(size_t)(r0 + (i>>5))*1024 + bs + (i&31)];
      __syncthreads();
      for (int i = tid; i < 1024; i += 256){
        int j = i>>5, cc2 = i&31;
        float2 acc = make_float2(0.f, 0.f);
        #pragma unroll
        for (int kk = 0; kk < 32; ++kk){
          float2 bv = Bi[j][kk], sv = Pr[kk][cc2];
          acc.x += bv.x*sv.x - bv.y*sv.y;
          acc.y += bv.x*sv.y + bv.y*sv.x;
        }
        T1[j][cc2] = acc;
      }
      __syncthreads();
      const int cc = tid & 31;
      float2 t1c[32];
      #pragma unroll
      for (int j = 0; j < 32; ++j) t1c[j] = T1[j][cc];
      #pragma unroll 4
      for (int i = 0; i < 16; ++i){
        int idx = tid + i*256;
        int rr = idx >> 5;
        int r = r0 + rr, c = c0 + cc;
        float2 nv;
        if (r >= bs && r < bs+32){
          nv = T1[r-bs][cc];
        } else {
          nv = aug[(size_t)r*1024 + c];
          #pragma unroll
          for (int j = 0; j < 32; ++j){
            float2 pq = Pc[rr][j], tt = t1c[j];
            nv.x -= pq.x*tt.x - pq.y*tt.y;
            nv.y -= pq.x*tt.y + pq.y*tt.x;
          }
        }
        aug[(size_t)r*1024 + c] = nv;
        int rn = r - (bs+32);
        if (rn >= 0 && rn < 32){
          prout[(size_t)rn*1024 + c] = nv;
          if (panel) Nd[rn][cc] = nv;     // stash next diagonal block
        }
      }
      if (panel) havePanel = true;
    }
    if (havePanel){
      __syncthreads();
      for (int i = tid; i < 1024; i += 256){
        int r = i>>5, c = i&31;
        Pr[r][c] = make_float2((r==c) ? 1.f : 0.f, 0.f);
      }
      __syncthreads();
      gj32(Nd, Pr, fcol, tid);
      for (int i = tid; i < 1024; i += 256) bout[i] = Pr[i>>5][i&31];
    }
    GBAR();
  }

  // ---- build MINV (bf16, row-interleaved real embedding) ----
  for (int i = blk*256 + tid; i < 1048576; i += NB_INV*256){
    int row = i >> 10, col = i & 1023;
    int m = row >> 1, irow = row & 1;
    int k = col & 511, icol = col >> 9;
    float2 a = aug[(size_t)m*1024 + 512 + k];
    float v;
    if (!irow) v = icol ? -a.y : a.x;
    else       v = icol ?  a.x : a.y;
    Mi[i] = f2b(v);
  }
}

// ---------------- GEMM: 256x256 tile, 8-wave, BK=32, 4-deep LDS ring ----------------
enum { EPI_BF16 = 0, EPI_ADDXC = 3, EPI_OUTF32 = 4, EPI_AX = 5 };

#define MFMA_BF16(a,b,c) __builtin_amdgcn_mfma_f32_16x16x32_bf16(a,b,c,0,0,0)

template<int EPI>
__global__ __launch_bounds__(512, 2) void gemm256(
    const u16* __restrict__ A, const u16* __restrict__ B,
    int K, int NT, int N, int byShift,
    void* __restrict__ C, void* __restrict__ aux0, void* __restrict__ aux1,
    void* __restrict__ aux2)
{
  extern __shared__ u16 LDS[];   // 65536 u16 = 128 KB
  const int tid = threadIdx.x;
  const int w = tid >> 6, lane = tid & 63;
  const int wm = w >> 2, wn = w & 3;
  const int fr = lane & 15, kg = lane >> 4;

  const int cpx = gridDim.x >> 3;
  const int bid = blockIdx.x;
  const int swz = (bid & 7)*cpx + (bid >> 3);
  const int by = swz & ((1 << byShift) - 1), bx = swz >> byShift;
  const size_t arow0 = (size_t)bx * 256;
  const int bcol0 = by * 256;

  const int rL = w*16 + (lane >> 2);
  const int glog = (lane & 3) ^ ((lane >> 3) & 3);
  const u16* Asrc = A + (arow0 + rL)*(size_t)K + glog*8;
  const u16* Bsrc = B + ((size_t)(bcol0 + rL))*K + glog*8;
  const size_t KH = (size_t)128 * K;
  const int sdst = w*512;

  const int goff = (kg ^ ((fr >> 1) & 3)) * 8;
  const int aro = wm*4096 + fr*32 + goff;
  const int bro = 32768 + (wn>>1)*4096 + (wn&1)*2048 + fr*32 + goff;

  f32x4 acc[8][4] = {};
  bf16x8 bfr[4];

  auto STG_A = [&](int kt){
    int bo = (kt & 3)*8192;
    #pragma unroll
    for (int h = 0; h < 2; ++h)
      __builtin_amdgcn_global_load_lds((gaddr_t)(Asrc + h*KH + kt*32),
          (laddr_t)(LDS + bo + h*4096 + sdst), 16, 0, 0);
  };
  auto STG_B = [&](int kt){
    int bo = 32768 + (kt & 3)*8192;
    #pragma unroll
    for (int h = 0; h < 2; ++h)
      __builtin_amdgcn_global_load_lds((gaddr_t)(Bsrc + h*KH + kt*32),
          (laddr_t)(LDS + bo + h*4096 + sdst), 16, 0, 0);
  };

  auto TILE = [&](int kt, int stg, int wait){
    const int ab = (kt & 3)*8192 + aro;
    const int bb = (kt & 3)*8192 + bro;
    bf16x8 af[4];
    #pragma unroll
    for (int m = 0; m < 4; ++m) af[m] = *(const bf16x8*)&LDS[ab + m*512];
    #pragma unroll
    for (int n = 0; n < 4; ++n) bfr[n] = *(const bf16x8*)&LDS[bb + n*512];
    if (stg) STG_A(kt + 3);
    __builtin_amdgcn_s_barrier();
    __builtin_amdgcn_s_setprio(1);
    #pragma unroll
    for (int m = 0; m < 4; ++m)
      #pragma unroll
      for (int n = 0; n < 4; ++n)
        acc[m][n] = MFMA_BF16(af[m], bfr[n], acc[m][n]);
    __builtin_amdgcn_s_setprio(0);
    __builtin_amdgcn_s_barrier();
    #pragma unroll
    for (int m = 0; m < 4; ++m) af[m] = *(const bf16x8*)&LDS[ab + (m+4)*512];
    if (stg) STG_B(kt + 3);
    __builtin_amdgcn_s_barrier();
    __builtin_amdgcn_s_setprio(1);
    #pragma unroll
    for (int m = 0; m < 4; ++m)
      #pragma unroll
      for (int n = 0; n < 4; ++n)
        acc[m+4][n] = MFMA_BF16(af[m], bfr[n], acc[m+4][n]);
    __builtin_amdgcn_s_setprio(0);
    if (wait == 2){ asm volatile("s_waitcnt vmcnt(8)" ::: "memory"); }
    else if (wait == 1){ asm volatile("s_waitcnt vmcnt(4)" ::: "memory"); }
    else if (wait == 0){ asm volatile("s_waitcnt vmcnt(0)" ::: "memory"); }
    __builtin_amdgcn_sched_barrier(0);
    __builtin_amdgcn_s_barrier();
  };

  STG_A(0); STG_B(0); STG_A(1); STG_B(1); STG_A(2); STG_B(2);
  asm volatile("s_waitcnt vmcnt(8)" ::: "memory");
  __builtin_amdgcn_sched_barrier(0);
  __builtin_amdgcn_s_barrier();

  #pragma unroll 1
  for (int kt = 0; kt < NT - 3; ++kt) TILE(kt, 1, 2);
  TILE(NT-3, 0, 1);
  TILE(NT-2, 0, 0);
  TILE(NT-1, 0, -1);

  const int rbase = wm*128 + (lane >> 4)*4;
  const int cbase = wn*64 + fr;
  #pragma unroll
  for (int M = 0; M < 8; ++M){
    #pragma unroll
    for (int Np = 0; Np < 4; ++Np){
      #pragma unroll
      for (int j = 0; j < 4; ++j){
        float v = acc[M][Np][j];
        size_t gr = arow0 + rbase + M*16 + j;
        int gc = bcol0 + cbase + Np*16;
        if constexpr (EPI == EPI_BF16){
          ((u16*)C)[gr*(size_t)N + gc] = f2b(v);
        } else if constexpr (EPI == EPI_OUTF32){
          ((float*)C)[gr*(size_t)N + gc] = v;
        } else if constexpr (EPI == EPI_ADDXC){
          float xc = b2f(((const u16*)aux0)[gr*512 + gc]);
          ((u16*)C)[gr*512 + gc] = f2b(v + xc);
        } else { // EPI_AX
          float pv = __shfl_xor(v, 1);
          int odd = lane & 1;
          float re = odd ? pv : v;
          float im = odd ? v : pv;
          float m2 = re*re + im*im;
          if (gc < 1024){
            int mh = gc >> 1;
            float sc = m2 > 0.f ? sqrtf(m2)/(1.f + m2) : 0.f;  // sigmoid(log m) = m/(1+m)
            if (!odd){
              unsigned pk = (unsigned)f2b(re*sc) | ((unsigned)f2b(im*sc) << 16);
              ((unsigned*)aux0)[gr*512 + mh] = pk;             // interleaved complex a
            }
          } else {
            int mh = (gc - 1024) >> 1;
            float sc = sqrtf(m2);                              // xc = x2 * sqrt(m)
            u16 ob = f2b(v * sc);
            if (!odd) ((u16*)aux1)[gr*512 + mh] = ob;          // xc_re
            int t = (int)(gr & 4095);
            if (t != 4095)                                     // x_roll[t+1] = xc[t]
              ((u16*)aux2)[(gr+1)*1024 + (odd ? 512 + mh : mh)] = ob;
          }
        }
      }
    }
  }
}

// ---------------- scan: s_t = a_t*(s_{t-1}+u_t), chunked 3-phase ----------------
__global__ void scan_p1(const unsigned* __restrict__ aint, const unsigned* __restrict__ uint_,
                        float4* __restrict__ agg){
  int idx = blockIdx.x*256 + threadIdx.x;   // 4*64*512 = 131072
  int m = idx & 511, chunk = (idx >> 9) & 63, b = idx >> 15;
  size_t row = (size_t)b*4096 + chunk*64;
  float px=1.f, py=0.f, sx=0.f, sy=0.f;
  for (int i = 0; i < 64; ++i, ++row){
    unsigned av = aint[row*512 + m];
    unsigned uv = uint_[row*512 + m];
    float ar = b2f((u16)av), ai = b2f((u16)(av>>16));
    float ur = b2f((u16)uv), ui = b2f((u16)(uv>>16));
    float tx2 = sx + ur, ty2 = sy + ui;
    sx = ar*tx2 - ai*ty2; sy = ar*ty2 + ai*tx2;
    float np = px*ar - py*ai; py = px*ai + py*ar; px = np;
  }
  agg[((size_t)(b*512+m))*64 + chunk] = make_float4(px,py,sx,sy);
}
__global__ void scan_p2(const float4* __restrict__ agg, float2* __restrict__ carry){
  int seq = blockIdx.x*256 + threadIdx.x;   // 2048
  float sx = 0.f, sy = 0.f;
  for (int c = 0; c < 64; ++c){
    carry[(size_t)seq*64 + c] = make_float2(sx, sy);
    float4 g = agg[(size_t)seq*64 + c];
    float nx = g.x*sx - g.y*sy + g.z;
    sy = g.x*sy + g.y*sx + g.w; sx = nx;
  }
}
__global__ void scan_p3(const unsigned* __restrict__ aint, const unsigned* __restrict__ uint_,
                        const float2* __restrict__ carry, unsigned* __restrict__ sout){
  int idx = blockIdx.x*256 + threadIdx.x;
  int m = idx & 511, chunk = (idx >> 9) & 63, b = idx >> 15;
  size_t row = (size_t)b*4096 + chunk*64;
  float2 c0 = carry[((size_t)(b*512+m))*64 + chunk];
  float sx = c0.x, sy = c0.y;
  for (int i = 0; i < 64; ++i, ++row){
    unsigned av = aint[row*512 + m];
    unsigned uv = uint_[row*512 + m];
    float ar = b2f((u16)av), ai = b2f((u16)(av>>16));
    float ur = b2f((u16)uv), ui = b2f((u16)(uv>>16));
    float tx2 = sx + ur, ty2 = sy + ui;
    sx = ar*tx2 - ai*ty2; sy = ar*ty2 + ai*tx2;
    sout[row*512 + m] = (unsigned)f2b(sx) | ((unsigned)f2b(sy) << 16);
  }
}

// ---------------- host ----------------
extern "C" void kernel_launch(void* const* d_in, const int* in_sizes, int n_in,
                              void* d_out, int out_size, void* d_ws, size_t ws_size,
                              hipStream_t stream){
  (void)in_sizes; (void)n_in; (void)out_size; (void)ws_size;
  const float* x   = (const float*)d_in[0];
  const float* wa  = (const float*)d_in[1];
  const float* wx  = (const float*)d_in[2];
  const float* wo  = (const float*)d_in[3];
  const float* vr  = (const float*)d_in[4];
  const float* vi  = (const float*)d_in[5];
  const float* lhr = (const float*)d_in[6];
  const float* lhi = (const float*)d_in[7];

  char* ws = (char*)d_ws;
  const size_t SB = 16384ull*1024*2;      // 33.5 MB
  const size_t HB = SB/2;
  u16* Xb    = (u16*)(ws);                // later reused as U
  unsigned* AINT = (unsigned*)(ws + SB);  // interleaved a ; later HRE
  u16* XROLL = (u16*)(ws + 2*SB);         // later reused as S
  u16* XCRE  = (u16*)(ws + 3*SB);
  char* p = ws + 3*SB + HB;
  u16* WABb  = (u16*)p; p += 4194304;     // [WA;WX] 2048x1024 bf16
  u16* MINV  = (u16*)p; p += 2097152;
  u16* MV4   = (u16*)p; p += 1048576;
  u16* WOUTb = (u16*)p; p += 1048576;
  float2* AUG   = (float2*)p; p += 4194304;
  float2* PROWA = (float2*)p; p += 262144;
  float2* PROWB = (float2*)p; p += 262144;
  float2* BINV0 = (float2*)p; p += 8192;
  float2* BINV1 = (float2*)p; p += 8192;
  float4* AGG   = (float4*)p; p += 2048ull*64*16;
  float2* CARRY = (float2*)p; p += 2048ull*64*8;
  int*    BAR   = (int*)p;   p += 256;
  u16* U   = Xb;
  u16* S   = XROLL;
  u16* HRE = (u16*)AINT;

  hipMemsetAsync(BAR, 0, 256, stream);

  cast_all<<<2048,256,0,stream>>>(x, wa, wx, wo, vr, vi, lhr, lhi,
                                  Xb, WABb, WOUTb, MV4, XROLL);

  inv_persist<<<NB_INV,256,0,stream>>>(vr, vi, AUG, PROWA, PROWB, BINV0, BINV1,
                                       MINV, BAR);

  const size_t GLDS = 131072;
  // fused gate+input projection: C cols 0..1023 = a2 (gate), 1024..2047 = x2
  gemm256<EPI_AX><<<512,512,GLDS,stream>>>(Xb, WABb, 1024, 32, 2048, 3,
                                           nullptr, (void*)AINT, (void*)XCRE, (void*)XROLL);
  gemm256<EPI_BF16><<<256,512,GLDS,stream>>>(XROLL, MINV, 1024, 32, 1024, 2,
                                             (void*)U, nullptr, nullptr, nullptr);

  scan_p1<<<512,256,0,stream>>>((const unsigned*)AINT, (const unsigned*)U, AGG);
  scan_p2<<<8,256,0,stream>>>(AGG, CARRY);
  scan_p3<<<512,256,0,stream>>>((const unsigned*)AINT, (const unsigned*)U, CARRY, (unsigned*)S);

  gemm256<EPI_ADDXC><<<128,512,GLDS,stream>>>(S, MV4, 1024, 32, 512, 1,
                                              (void*)HRE, (void*)XCRE, nullptr, nullptr);
  gemm256<EPI_OUTF32><<<256,512,GLDS,stream>>>(HRE, WOUTb, 512, 16, 1024, 2,
                                               d_out, nullptr, nullptr, nullptr);
}